// Round 4
// baseline (556.943 us; speedup 1.0000x reference)
//
#include <hip/hip_runtime.h>
#include <hip/hip_bf16.h>

typedef unsigned short u16;
typedef __bf16 bf16x8 __attribute__((ext_vector_type(8)));
typedef float floatx4 __attribute__((ext_vector_type(4)));
typedef unsigned short u16x4 __attribute__((ext_vector_type(4)));
typedef unsigned short u16x8 __attribute__((ext_vector_type(8)));

__device__ __forceinline__ float b2f(u16 v) {
  unsigned u = ((unsigned)v) << 16;
  return __builtin_bit_cast(float, u);
}
__device__ __forceinline__ u16 f2b(float f) {
  unsigned u = __builtin_bit_cast(unsigned, f);
  unsigned r = (u + 0x7FFFu + ((u >> 16) & 1u)) >> 16;
  return (u16)r;
}
__device__ __forceinline__ void cp16(const u16* g, u16* l) {
  __builtin_amdgcn_global_load_lds(
      (const __attribute__((address_space(1))) unsigned int*)g,
      (__attribute__((address_space(3))) unsigned int*)l, 16, 0, 0);
}

// ---------------------------------------------------------------------------
// Big GEMM: C[M,1024] = A(bf16) @ BT(bf16)^T + bias(f32) [+ summ f32]
// grid: (8 col-tiles, M/128 row-tiles, nmat) — col-fastest for A-tile L2 reuse
// ---------------------------------------------------------------------------
struct GemmArgs {
  const u16* A;
  const u16* BT0; const u16* BT1; const u16* BT2;
  const float* b0; const float* b1; const float* b2;
  const float* summ;   // nullable
  int srow0;
  u16* C0; u16* C1; u16* C2;
  float* Cf;           // f32 output (single-matrix launches only)
};

__global__ __launch_bounds__(256, 2) void gemm_bt(GemmArgs g) {
  const int z = blockIdx.z;
  const u16* A      = g.A;
  const u16* BT     = (z == 0) ? g.BT0 : (z == 1 ? g.BT1 : g.BT2);
  const float* bias = (z == 0) ? g.b0  : (z == 1 ? g.b1  : g.b2);
  u16* C            = (z == 0) ? g.C0  : (z == 1 ? g.C1  : g.C2);

  __shared__ u16 As[128 * 32];
  __shared__ u16 Bs[128 * 32];

  const int tid  = threadIdx.x;
  const int lane = tid & 63;
  const int wave = tid >> 6;
  const int quad = lane >> 4;
  const int cl   = lane & 15;
  const int wm   = wave & 1;
  const int wn   = wave >> 1;

  const size_t col0 = (size_t)blockIdx.x * 128;
  const size_t row0 = (size_t)blockIdx.y * 128;

  const int srow = lane >> 2;
  const int soff = (lane & 3) << 3;

  const u16* gA0 = A + (row0 + (size_t)(wave * 16 + srow)) * 1024 + soff;
  const u16* gA1 = gA0 + (size_t)64 * 1024;
  const u16* gB0 = BT + (col0 + (size_t)(wave * 16 + srow)) * 1024 + soff;
  const u16* gB1 = gB0 + (size_t)64 * 1024;
  u16* lA0 = As + wave * 512 + lane * 8;
  u16* lA1 = lA0 + 2048;
  u16* lB0 = Bs + wave * 512 + lane * 8;
  u16* lB1 = lB0 + 2048;

  floatx4 acc[4][4] = {};

  for (int kt = 0; kt < 1024; kt += 32) {
    __syncthreads();
    cp16(gA0, lA0); cp16(gA1, lA1);
    cp16(gB0, lB0); cp16(gB1, lB1);
    gA0 += 32; gA1 += 32; gB0 += 32; gB1 += 32;
    __syncthreads();
    bf16x8 af[4], bfr[4];
#pragma unroll
    for (int m = 0; m < 4; ++m)
      af[m] = *(const bf16x8*)&As[(wm * 64 + m * 16 + cl) * 32 + quad * 8];
#pragma unroll
    for (int n = 0; n < 4; ++n)
      bfr[n] = *(const bf16x8*)&Bs[(wn * 64 + n * 16 + cl) * 32 + quad * 8];
#pragma unroll
    for (int m = 0; m < 4; ++m)
#pragma unroll
      for (int n = 0; n < 4; ++n)
        acc[m][n] = __builtin_amdgcn_mfma_f32_16x16x32_bf16(af[m], bfr[n],
                                                            acc[m][n], 0, 0, 0);
  }

  const float* summ = g.summ;
#pragma unroll
  for (int m = 0; m < 4; ++m) {
    const size_t rbase = row0 + wm * 64 + m * 16 + quad * 4;
#pragma unroll
    for (int n = 0; n < 4; ++n) {
      const size_t c = col0 + wn * 64 + n * 16 + cl;
      const float bb = bias[c];
#pragma unroll
      for (int e = 0; e < 4; ++e) {
        float v = acc[m][n][e] + bb;
        if (summ)
          v += summ[(size_t)((int)((rbase + e) >> 8) + g.srow0) * 1024 + c];
        if (g.Cf) g.Cf[(rbase + e) * 1024 + c] = v;
        else      C[(rbase + e) * 1024 + c] = f2b(v);
      }
    }
  }
}

// ---------------------------------------------------------------------------
// Small GEMM: C[64,1024] = A[64,1024] @ BT^T + bias. No LDS, no barriers.
// Wave w owns m-tile w (rows w*16..w*16+15), full K. grid (16 col-tiles, 1, nmat)
// ---------------------------------------------------------------------------
struct SmallArgs {
  const void* A;       // bf16 or f32 [64][1024]
  const u16* BT0; const u16* BT1; const u16* BT2;
  const float* b0; const float* b1; const float* b2;
  float a_scale; int a_f32;
  u16* C0; u16* C1; u16* C2;
  float* Cf;           // f32 out (single-matrix launches only)
};

__global__ __launch_bounds__(256, 2) void small_gemm(SmallArgs s) {
  const int z = blockIdx.z;
  const u16* BT     = (z == 0) ? s.BT0 : (z == 1 ? s.BT1 : s.BT2);
  const float* bias = (z == 0) ? s.b0  : (z == 1 ? s.b1  : s.b2);
  u16* C            = (z == 0) ? s.C0  : (z == 1 ? s.C1  : s.C2);

  const int tid  = threadIdx.x;
  const int lane = tid & 63;
  const int w    = tid >> 6;
  const int quad = lane >> 4;
  const int cl   = lane & 15;
  const int col0 = blockIdx.x * 64;
  const int arow = w * 16 + cl;

  floatx4 acc[4] = {};
  for (int k0 = 0; k0 < 1024; k0 += 32) {
    bf16x8 af;
    if (s.a_f32) {
      const float* ap = (const float*)s.A + (size_t)arow * 1024 + k0 + quad * 8;
      float4 v0 = *(const float4*)ap;
      float4 v1 = *(const float4*)(ap + 4);
      u16x8 t;
      t[0] = f2b(v0.x * s.a_scale); t[1] = f2b(v0.y * s.a_scale);
      t[2] = f2b(v0.z * s.a_scale); t[3] = f2b(v0.w * s.a_scale);
      t[4] = f2b(v1.x * s.a_scale); t[5] = f2b(v1.y * s.a_scale);
      t[6] = f2b(v1.z * s.a_scale); t[7] = f2b(v1.w * s.a_scale);
      af = __builtin_bit_cast(bf16x8, t);
    } else {
      af = *(const bf16x8*)((const u16*)s.A + (size_t)arow * 1024 + k0 + quad * 8);
    }
#pragma unroll
    for (int n = 0; n < 4; ++n) {
      const bf16x8 bf_ =
          *(const bf16x8*)&BT[(size_t)(col0 + n * 16 + cl) * 1024 + k0 + quad * 8];
      acc[n] = __builtin_amdgcn_mfma_f32_16x16x32_bf16(af, bf_, acc[n], 0, 0, 0);
    }
  }
#pragma unroll
  for (int n = 0; n < 4; ++n) {
    const int c = col0 + n * 16 + cl;
    const float bb = bias[c];
#pragma unroll
    for (int e = 0; e < 4; ++e) {
      const int r = w * 16 + quad * 4 + e;
      const float v = acc[n][e] + bb;
      if (s.Cf) s.Cf[(size_t)r * 1024 + c] = v;
      else      C[(size_t)r * 1024 + c] = f2b(v);
    }
  }
}

// ---------------------------------------------------------------------------
// Local block attention v2. grid (4 qtiles, 16 heads, nblk), 256 threads.
// All 256 keys staged once; Q frags in regs; 3 barriers total.
// ---------------------------------------------------------------------------
__global__ __launch_bounds__(256, 2) void local_attn(
    const u16* __restrict__ Q, const u16* __restrict__ Kt,
    const u16* __restrict__ Vt, const float* __restrict__ pbias,
    u16* __restrict__ ctx) {
  const int qt  = blockIdx.x;
  const int h   = blockIdx.y;
  const int blk = blockIdx.z;
  const int tid  = threadIdx.x;
  const int lane = tid & 63;
  const int w    = tid >> 6;
  const int quad = lane >> 4;
  const int cl   = lane & 15;

  // K view: [256][72]; V^T view (after reuse): [64][264]
  __shared__ u16 KV[256 * 72];          // 36864 B
  __shared__ u16 P[64 * 136];           // 17408 B (one 128-key half)

  const size_t tok0  = (size_t)blk * 256;
  const size_t qrow0 = tok0 + qt * 64;
  const int hc = h * 64;

  // Q fragments straight from global (wave-private rows)
  const u16* qrow = Q + (qrow0 + w * 16 + cl) * 1024 + hc;
  const bf16x8 aq0 = *(const bf16x8*)&qrow[quad * 8];
  const bf16x8 aq1 = *(const bf16x8*)&qrow[32 + quad * 8];

  // stage K fully: [256 keys][64 dh]
  for (int i = tid; i < 2048; i += 256) {
    const int row = i >> 3, c8 = (i & 7) * 8;
    *(u16x8*)&KV[row * 72 + c8] =
        *(const u16x8*)&Kt[(tok0 + row) * 1024 + hc + c8];
  }
  __syncthreads();

  floatx4 accS[16] = {};  // rows w*16+quad*4+r, cols n16*16+cl
#pragma unroll
  for (int n16 = 0; n16 < 16; ++n16) {
    const bf16x8 bk0 = *(const bf16x8*)&KV[(n16 * 16 + cl) * 72 + quad * 8];
    const bf16x8 bk1 = *(const bf16x8*)&KV[(n16 * 16 + cl) * 72 + 32 + quad * 8];
    accS[n16] = __builtin_amdgcn_mfma_f32_16x16x32_bf16(aq0, bk0, accS[n16], 0, 0, 0);
    accS[n16] = __builtin_amdgcn_mfma_f32_16x16x32_bf16(aq1, bk1, accS[n16], 0, 0, 0);
  }

  // softmax over 256 keys
  float mrow[4] = {-1e30f, -1e30f, -1e30f, -1e30f};
#pragma unroll
  for (int r = 0; r < 4; ++r) {
    const float* brow = pbias + ((size_t)h << 16) +
                        (size_t)(qt * 64 + w * 16 + quad * 4 + r) * 256 + cl;
#pragma unroll
    for (int n = 0; n < 16; ++n) {
      float sv = accS[n][r] * 0.125f + brow[n * 16];
      accS[n][r] = sv;
      mrow[r] = fmaxf(mrow[r], sv);
    }
  }
#pragma unroll
  for (int r = 0; r < 4; ++r)
#pragma unroll
    for (int st = 1; st < 16; st <<= 1)
      mrow[r] = fmaxf(mrow[r], __shfl_xor(mrow[r], st));
  float lsum[4] = {0.f, 0.f, 0.f, 0.f};
#pragma unroll
  for (int n = 0; n < 16; ++n)
#pragma unroll
    for (int r = 0; r < 4; ++r) {
      float p = exp2f((accS[n][r] - mrow[r]) * 1.44269504f);
      accS[n][r] = p;
      lsum[r] += p;
    }
#pragma unroll
  for (int r = 0; r < 4; ++r)
#pragma unroll
    for (int st = 1; st < 16; st <<= 1)
      lsum[r] += __shfl_xor(lsum[r], st);

  __syncthreads();  // everyone done reading K before V^T overwrites it

  // stage V^T: [64 dh][256 keys] stride 264; thread tid owns key=tid
  for (int t = 0; t < 8; ++t) {
    const u16x8 v = *(const u16x8*)&Vt[(tok0 + tid) * 1024 + hc + t * 8];
#pragma unroll
    for (int j = 0; j < 8; ++j) KV[(t * 8 + j) * 264 + tid] = v[j];
  }
  __syncthreads();

  // O = P @ V in two 128-key halves; P rows are wave-private (no barriers)
  floatx4 accO[4] = {};
#pragma unroll
  for (int hf = 0; hf < 2; ++hf) {
#pragma unroll
    for (int gi = 0; gi < 8; ++gi)
#pragma unroll
      for (int r = 0; r < 4; ++r)
        P[(w * 16 + quad * 4 + r) * 136 + gi * 16 + cl] =
            f2b(accS[hf * 8 + gi][r]);
#pragma unroll
    for (int kk = 0; kk < 4; ++kk) {
      const bf16x8 ap =
          *(const bf16x8*)&P[(w * 16 + cl) * 136 + kk * 32 + quad * 8];
#pragma unroll
      for (int nd = 0; nd < 4; ++nd) {
        const bf16x8 bv = *(const bf16x8*)&KV[(nd * 16 + cl) * 264 +
                                              hf * 128 + kk * 32 + quad * 8];
        accO[nd] = __builtin_amdgcn_mfma_f32_16x16x32_bf16(ap, bv, accO[nd],
                                                           0, 0, 0);
      }
    }
  }

  float inv[4];
#pragma unroll
  for (int r = 0; r < 4; ++r) inv[r] = 1.0f / lsum[r];
#pragma unroll
  for (int nd = 0; nd < 4; ++nd)
#pragma unroll
    for (int r = 0; r < 4; ++r)
      ctx[(qrow0 + w * 16 + quad * 4 + r) * 1024 + hc + nd * 16 + cl] =
          f2b(accO[nd][r] * inv[r]);
}

// ---------------------------------------------------------------------------
// Fused x f32->bf16 conversion + block-mean partial sums (atomic f32)
// grid (4 token-quarters, 64 blocks), 256 threads (4 d-cols each)
// ---------------------------------------------------------------------------
__global__ void cvtx_mean(const float* __restrict__ x, u16* __restrict__ xb,
                          float* __restrict__ xmf) {
  const int tq = blockIdx.x;
  const int g  = blockIdx.y;
  const int d0 = threadIdx.x * 4;
  const size_t trow = (size_t)g * 256 + tq * 64;
  const float* p = x + trow * 1024 + d0;
  u16* q = xb + trow * 1024 + d0;
  float4 s = {0.f, 0.f, 0.f, 0.f};
  for (int t = 0; t < 64; ++t) {
    float4 v = *(const float4*)(p + (size_t)t * 1024);
    s.x += v.x; s.y += v.y; s.z += v.z; s.w += v.w;
    u16x4 o;
    o[0] = f2b(v.x); o[1] = f2b(v.y); o[2] = f2b(v.z); o[3] = f2b(v.w);
    *(u16x4*)(q + (size_t)t * 1024) = o;
  }
  atomicAdd(&xmf[g * 1024 + d0 + 0], s.x);
  atomicAdd(&xmf[g * 1024 + d0 + 1], s.y);
  atomicAdd(&xmf[g * 1024 + d0 + 2], s.z);
  atomicAdd(&xmf[g * 1024 + d0 + 3], s.w);
}

__global__ void summ_attn(const u16* __restrict__ SQ, const u16* __restrict__ SK,
                          const u16* __restrict__ SV, u16* __restrict__ sctx) {
  const int b = blockIdx.x >> 4;
  const int h = blockIdx.x & 15;
  const int t = threadIdx.x;  // 64 threads
  __shared__ float Qf[16][64];
  __shared__ float Kf[16][64];
  __shared__ float Vf[16][64];
  __shared__ float sc[16][16];
  for (int i = t; i < 1024; i += 64) {
    const int r = i >> 6, d = i & 63;
    const size_t off = (size_t)(b * 16 + r) * 1024 + h * 64 + d;
    Qf[r][d] = b2f(SQ[off]);
    Kf[r][d] = b2f(SK[off]);
    Vf[r][d] = b2f(SV[off]);
  }
  __syncthreads();
  {
    const int i = t >> 2, j0 = t & 3;
#pragma unroll
    for (int jj = 0; jj < 4; ++jj) {
      const int j = j0 + jj * 4;
      float s = 0.f;
      for (int d = 0; d < 64; ++d) s += Qf[i][d] * Kf[j][d];
      sc[i][j] = s * 0.125f;
    }
  }
  __syncthreads();
  if (t < 16) {
    float m = -1e30f;
    for (int j = 0; j < 16; ++j) m = fmaxf(m, sc[t][j]);
    float l = 0.f;
    for (int j = 0; j < 16; ++j) {
      float p = exp2f((sc[t][j] - m) * 1.44269504f);
      sc[t][j] = p;
      l += p;
    }
    const float inv = 1.0f / l;
    for (int j = 0; j < 16; ++j) sc[t][j] *= inv;
  }
  __syncthreads();
  {
    const int i = t >> 2, d0 = (t & 3) * 16;
    for (int dd = 0; dd < 16; ++dd) {
      float a = 0.f;
      for (int j = 0; j < 16; ++j) a += sc[i][j] * Vf[j][d0 + dd];
      sctx[(size_t)(b * 16 + i) * 1024 + h * 64 + d0 + dd] = f2b(a);
    }
  }
}

// 9x [1024,1024] f32 -> bf16 transposed ("BT": dst[n][k] = src[k][n])
struct TPtrs { const float* src[9]; u16* dst[9]; };

__global__ void cvt_transpose9(TPtrs p) {
  const float* src = p.src[blockIdx.z];
  u16* dst         = p.dst[blockIdx.z];
  __shared__ u16 tile[64][72];
  const int r0 = blockIdx.x * 64, c0 = blockIdx.y * 64;
  for (int i = threadIdx.x; i < 1024; i += 256) {
    const int row = i >> 4, c4 = (i & 15) * 4;
    float4 v = *(const float4*)&src[(size_t)(r0 + row) * 1024 + c0 + c4];
    tile[row][c4 + 0] = f2b(v.x);
    tile[row][c4 + 1] = f2b(v.y);
    tile[row][c4 + 2] = f2b(v.z);
    tile[row][c4 + 3] = f2b(v.w);
  }
  __syncthreads();
  for (int i = threadIdx.x; i < 512; i += 256) {
    const int row = i >> 3, c8 = (i & 7) * 8;
    u16x8 v;
#pragma unroll
    for (int j = 0; j < 8; ++j) v[j] = tile[c8 + j][row];
    *(u16x8*)&dst[(size_t)(c0 + row) * 1024 + r0 + c8] = v;
  }
}

// ---------------------------------------------------------------------------
extern "C" void kernel_launch(void* const* d_in, const int* in_sizes, int n_in,
                              void* d_out, int out_size, void* d_ws, size_t ws_size,
                              hipStream_t stream) {
  const float* x    = (const float*)d_in[0];
  const float* lqw  = (const float*)d_in[1];
  const float* lqb  = (const float*)d_in[2];
  const float* lkw  = (const float*)d_in[3];
  const float* lkb  = (const float*)d_in[4];
  const float* lvw  = (const float*)d_in[5];
  const float* lvb  = (const float*)d_in[6];
  const float* low_ = (const float*)d_in[7];
  const float* lob  = (const float*)d_in[8];
  const float* pb   = (const float*)d_in[9];
  const float* sqw  = (const float*)d_in[10];
  const float* sqb  = (const float*)d_in[11];
  const float* skw  = (const float*)d_in[12];
  const float* skb  = (const float*)d_in[13];
  const float* svw  = (const float*)d_in[14];
  const float* svb  = (const float*)d_in[15];
  const float* sow  = (const float*)d_in[16];
  const float* sob  = (const float*)d_in[17];
  const float* smw  = (const float*)d_in[18];
  const float* smb  = (const float*)d_in[19];

  char* W = (char*)d_ws;
  size_t off = 0;
  u16* wt[9];
  for (int i = 0; i < 9; ++i) { wt[i] = (u16*)(W + off); off += (size_t)1024 * 1024 * 2; }
  u16* Xb    = (u16*)(W + off); off += (size_t)16384 * 1024 * 2;
  float* XMf = (float*)(W + off); off += (size_t)64 * 1024 * 4;
  u16* SMR   = (u16*)(W + off); off += (size_t)64 * 1024 * 2;
  u16* SQp   = (u16*)(W + off); off += (size_t)64 * 1024 * 2;
  u16* SKp   = (u16*)(W + off); off += (size_t)64 * 1024 * 2;
  u16* SVp   = (u16*)(W + off); off += (size_t)64 * 1024 * 2;
  u16* SCT   = (u16*)(W + off); off += (size_t)64 * 1024 * 2;
  float* SMM = (float*)(W + off); off += (size_t)64 * 1024 * 4;
  const size_t fixedB = off;

  int CH = 256;
  for (int c = 16384; c >= 256; c >>= 1) {
    if (fixedB + (size_t)4 * c * 1024 * 2 <= ws_size) { CH = c; break; }
  }
  u16* Qb  = (u16*)(W + fixedB);
  u16* Kb  = Qb + (size_t)CH * 1024;
  u16* Vb  = Kb + (size_t)CH * 1024;
  u16* CTX = Vb + (size_t)CH * 1024;

  TPtrs tp;
  tp.src[0] = lqw; tp.src[1] = lkw; tp.src[2] = lvw; tp.src[3] = low_;
  tp.src[4] = sqw; tp.src[5] = skw; tp.src[6] = svw; tp.src[7] = sow;
  tp.src[8] = smw;
  for (int i = 0; i < 9; ++i) tp.dst[i] = wt[i];
  cvt_transpose9<<<dim3(16, 16, 9), 256, 0, stream>>>(tp);

  hipMemsetAsync(XMf, 0, (size_t)64 * 1024 * 4, stream);
  cvtx_mean<<<dim3(4, 64), 256, 0, stream>>>(x, Xb, XMf);

  SmallArgs s1{};
  s1.A = XMf; s1.BT0 = s1.BT1 = s1.BT2 = wt[8];
  s1.b0 = s1.b1 = s1.b2 = smb;
  s1.a_scale = 1.0f / 256.0f; s1.a_f32 = 1;
  s1.C0 = s1.C1 = s1.C2 = SMR; s1.Cf = nullptr;
  small_gemm<<<dim3(16, 1, 1), 256, 0, stream>>>(s1);

  SmallArgs s2{};
  s2.A = SMR; s2.BT0 = wt[4]; s2.BT1 = wt[5]; s2.BT2 = wt[6];
  s2.b0 = sqb; s2.b1 = skb; s2.b2 = svb;
  s2.a_scale = 1.0f; s2.a_f32 = 0;
  s2.C0 = SQp; s2.C1 = SKp; s2.C2 = SVp; s2.Cf = nullptr;
  small_gemm<<<dim3(16, 1, 3), 256, 0, stream>>>(s2);

  summ_attn<<<dim3(64), 64, 0, stream>>>(SQp, SKp, SVp, SCT);

  SmallArgs s3{};
  s3.A = SCT; s3.BT0 = s3.BT1 = s3.BT2 = wt[7];
  s3.b0 = s3.b1 = s3.b2 = sob;
  s3.a_scale = 1.0f; s3.a_f32 = 0;
  s3.C0 = s3.C1 = s3.C2 = nullptr; s3.Cf = SMM;
  small_gemm<<<dim3(16, 1, 1), 256, 0, stream>>>(s3);

  for (int base = 0; base < 16384; base += CH) {
    GemmArgs g4{};
    g4.A = Xb + (size_t)base * 1024;
    g4.BT0 = wt[0]; g4.BT1 = wt[1]; g4.BT2 = wt[2];
    g4.b0 = lqb; g4.b1 = lkb; g4.b2 = lvb; g4.summ = nullptr; g4.srow0 = 0;
    g4.C0 = Qb; g4.C1 = Kb; g4.C2 = Vb; g4.Cf = nullptr;
    gemm_bt<<<dim3(8, CH / 128, 3), 256, 0, stream>>>(g4);

    local_attn<<<dim3(4, 16, CH / 256), 256, 0, stream>>>(Qb, Kb, Vb, pb, CTX);

    GemmArgs g5{};
    g5.A = CTX; g5.BT0 = g5.BT1 = g5.BT2 = wt[3];
    g5.b0 = g5.b1 = g5.b2 = lob; g5.summ = SMM; g5.srow0 = base >> 8;
    g5.C0 = g5.C1 = g5.C2 = nullptr;
    g5.Cf = (float*)d_out + (size_t)base * 1024;
    gemm_bt<<<dim3(8, CH / 128, 1), 256, 0, stream>>>(g5);
  }

  (void)in_sizes; (void)n_in; (void)out_size;
}

// Round 5
// 536.224 us; speedup vs baseline: 1.0386x; 1.0386x over previous
//
#include <hip/hip_runtime.h>
#include <hip/hip_bf16.h>

typedef unsigned short u16;
typedef __bf16 bf16x8 __attribute__((ext_vector_type(8)));
typedef float floatx4 __attribute__((ext_vector_type(4)));
typedef unsigned short u16x4 __attribute__((ext_vector_type(4)));
typedef unsigned short u16x8 __attribute__((ext_vector_type(8)));

__device__ __forceinline__ float b2f(u16 v) {
  unsigned u = ((unsigned)v) << 16;
  return __builtin_bit_cast(float, u);
}
__device__ __forceinline__ u16 f2b(float f) {
  unsigned u = __builtin_bit_cast(unsigned, f);
  unsigned r = (u + 0x7FFFu + ((u >> 16) & 1u)) >> 16;
  return (u16)r;
}
__device__ __forceinline__ void cp16(const u16* g, u16* l) {
  __builtin_amdgcn_global_load_lds(
      (const __attribute__((address_space(1))) unsigned int*)g,
      (__attribute__((address_space(3))) unsigned int*)l, 16, 0, 0);
}

// ---------------------------------------------------------------------------
// Big GEMM: C[M,1024] = A(bf16) @ BT(bf16)^T + bias(f32) [+ summ f32]
// grid: (M/128 row-tiles, 8 col-tiles, nmat).
// DO NOT swap x/y: row-tile on blockIdx.x makes the 8 col-tiles of a row-tile
// land on ONE XCD (ids r+128c ≡ r mod 8) -> A row-tile L2-reused 8x.
// Swapping measured +290 MB FETCH, +26 us (round 4).
// ---------------------------------------------------------------------------
struct GemmArgs {
  const u16* A;
  const u16* BT0; const u16* BT1; const u16* BT2;
  const float* b0; const float* b1; const float* b2;
  const float* summ;   // nullable
  int srow0;
  u16* C0; u16* C1; u16* C2;
  float* Cf;           // f32 output (single-matrix launches only)
};

__global__ __launch_bounds__(256, 2) void gemm_bt(GemmArgs g) {
  const int z = blockIdx.z;
  const u16* A      = g.A;
  const u16* BT     = (z == 0) ? g.BT0 : (z == 1 ? g.BT1 : g.BT2);
  const float* bias = (z == 0) ? g.b0  : (z == 1 ? g.b1  : g.b2);
  u16* C            = (z == 0) ? g.C0  : (z == 1 ? g.C1  : g.C2);

  __shared__ u16 As[128 * 32];
  __shared__ u16 Bs[128 * 32];

  const int tid  = threadIdx.x;
  const int lane = tid & 63;
  const int wave = tid >> 6;
  const int quad = lane >> 4;
  const int cl   = lane & 15;
  const int wm   = wave & 1;
  const int wn   = wave >> 1;

  const size_t row0 = (size_t)blockIdx.x * 128;
  const size_t col0 = (size_t)blockIdx.y * 128;

  const int srow = lane >> 2;
  const int soff = (lane & 3) << 3;

  const u16* gA0 = A + (row0 + (size_t)(wave * 16 + srow)) * 1024 + soff;
  const u16* gA1 = gA0 + (size_t)64 * 1024;
  const u16* gB0 = BT + (col0 + (size_t)(wave * 16 + srow)) * 1024 + soff;
  const u16* gB1 = gB0 + (size_t)64 * 1024;
  u16* lA0 = As + wave * 512 + lane * 8;
  u16* lA1 = lA0 + 2048;
  u16* lB0 = Bs + wave * 512 + lane * 8;
  u16* lB1 = lB0 + 2048;

  floatx4 acc[4][4] = {};

  for (int kt = 0; kt < 1024; kt += 32) {
    __syncthreads();
    cp16(gA0, lA0); cp16(gA1, lA1);
    cp16(gB0, lB0); cp16(gB1, lB1);
    gA0 += 32; gA1 += 32; gB0 += 32; gB1 += 32;
    __syncthreads();
    bf16x8 af[4], bfr[4];
#pragma unroll
    for (int m = 0; m < 4; ++m)
      af[m] = *(const bf16x8*)&As[(wm * 64 + m * 16 + cl) * 32 + quad * 8];
#pragma unroll
    for (int n = 0; n < 4; ++n)
      bfr[n] = *(const bf16x8*)&Bs[(wn * 64 + n * 16 + cl) * 32 + quad * 8];
#pragma unroll
    for (int m = 0; m < 4; ++m)
#pragma unroll
      for (int n = 0; n < 4; ++n)
        acc[m][n] = __builtin_amdgcn_mfma_f32_16x16x32_bf16(af[m], bfr[n],
                                                            acc[m][n], 0, 0, 0);
  }

  const float* summ = g.summ;
#pragma unroll
  for (int m = 0; m < 4; ++m) {
    const size_t rbase = row0 + wm * 64 + m * 16 + quad * 4;
#pragma unroll
    for (int n = 0; n < 4; ++n) {
      const size_t c = col0 + wn * 64 + n * 16 + cl;
      const float bb = bias[c];
#pragma unroll
      for (int e = 0; e < 4; ++e) {
        float v = acc[m][n][e] + bb;
        if (summ)
          v += summ[(size_t)((int)((rbase + e) >> 8) + g.srow0) * 1024 + c];
        if (g.Cf) g.Cf[(rbase + e) * 1024 + c] = v;
        else      C[(rbase + e) * 1024 + c] = f2b(v);
      }
    }
  }
}

// ---------------------------------------------------------------------------
// Small GEMM: C[64,1024] = A[64,1024] @ BT^T + bias. No LDS, no barriers.
// ---------------------------------------------------------------------------
struct SmallArgs {
  const void* A;       // bf16 or f32 [64][1024]
  const u16* BT0; const u16* BT1; const u16* BT2;
  const float* b0; const float* b1; const float* b2;
  float a_scale; int a_f32;
  u16* C0; u16* C1; u16* C2;
  float* Cf;           // f32 out (single-matrix launches only)
};

__global__ __launch_bounds__(256, 2) void small_gemm(SmallArgs s) {
  const int z = blockIdx.z;
  const u16* BT     = (z == 0) ? s.BT0 : (z == 1 ? s.BT1 : s.BT2);
  const float* bias = (z == 0) ? s.b0  : (z == 1 ? s.b1  : s.b2);
  u16* C            = (z == 0) ? s.C0  : (z == 1 ? s.C1  : s.C2);

  const int tid  = threadIdx.x;
  const int lane = tid & 63;
  const int w    = tid >> 6;
  const int quad = lane >> 4;
  const int cl   = lane & 15;
  const int col0 = blockIdx.x * 64;
  const int arow = w * 16 + cl;

  floatx4 acc[4] = {};
  for (int k0 = 0; k0 < 1024; k0 += 32) {
    bf16x8 af;
    if (s.a_f32) {
      const float* ap = (const float*)s.A + (size_t)arow * 1024 + k0 + quad * 8;
      float4 v0 = *(const float4*)ap;
      float4 v1 = *(const float4*)(ap + 4);
      u16x8 t;
      t[0] = f2b(v0.x * s.a_scale); t[1] = f2b(v0.y * s.a_scale);
      t[2] = f2b(v0.z * s.a_scale); t[3] = f2b(v0.w * s.a_scale);
      t[4] = f2b(v1.x * s.a_scale); t[5] = f2b(v1.y * s.a_scale);
      t[6] = f2b(v1.z * s.a_scale); t[7] = f2b(v1.w * s.a_scale);
      af = __builtin_bit_cast(bf16x8, t);
    } else {
      af = *(const bf16x8*)((const u16*)s.A + (size_t)arow * 1024 + k0 + quad * 8);
    }
#pragma unroll
    for (int n = 0; n < 4; ++n) {
      const bf16x8 bf_ =
          *(const bf16x8*)&BT[(size_t)(col0 + n * 16 + cl) * 1024 + k0 + quad * 8];
      acc[n] = __builtin_amdgcn_mfma_f32_16x16x32_bf16(af, bf_, acc[n], 0, 0, 0);
    }
  }
#pragma unroll
  for (int n = 0; n < 4; ++n) {
    const int c = col0 + n * 16 + cl;
    const float bb = bias[c];
#pragma unroll
    for (int e = 0; e < 4; ++e) {
      const int r = w * 16 + quad * 4 + e;
      const float v = acc[n][e] + bb;
      if (s.Cf) s.Cf[(size_t)r * 1024 + c] = v;
      else      C[(size_t)r * 1024 + c] = f2b(v);
    }
  }
}

// ---------------------------------------------------------------------------
// Local block attention v2. grid (4 qtiles, 16 heads, nblk), 256 threads.
// All 256 keys staged once; Q frags in regs; 3 barriers total.
// ---------------------------------------------------------------------------
__global__ __launch_bounds__(256, 2) void local_attn(
    const u16* __restrict__ Q, const u16* __restrict__ Kt,
    const u16* __restrict__ Vt, const float* __restrict__ pbias,
    u16* __restrict__ ctx) {
  const int qt  = blockIdx.x;
  const int h   = blockIdx.y;
  const int blk = blockIdx.z;
  const int tid  = threadIdx.x;
  const int lane = tid & 63;
  const int w    = tid >> 6;
  const int quad = lane >> 4;
  const int cl   = lane & 15;

  __shared__ u16 KV[256 * 72];          // K [256][72]; then V^T [64][264]
  __shared__ u16 P[64 * 136];           // one 128-key half of P

  const size_t tok0  = (size_t)blk * 256;
  const size_t qrow0 = tok0 + qt * 64;
  const int hc = h * 64;

  const u16* qrow = Q + (qrow0 + w * 16 + cl) * 1024 + hc;
  const bf16x8 aq0 = *(const bf16x8*)&qrow[quad * 8];
  const bf16x8 aq1 = *(const bf16x8*)&qrow[32 + quad * 8];

  for (int i = tid; i < 2048; i += 256) {
    const int row = i >> 3, c8 = (i & 7) * 8;
    *(u16x8*)&KV[row * 72 + c8] =
        *(const u16x8*)&Kt[(tok0 + row) * 1024 + hc + c8];
  }
  __syncthreads();

  floatx4 accS[16] = {};
#pragma unroll
  for (int n16 = 0; n16 < 16; ++n16) {
    const bf16x8 bk0 = *(const bf16x8*)&KV[(n16 * 16 + cl) * 72 + quad * 8];
    const bf16x8 bk1 = *(const bf16x8*)&KV[(n16 * 16 + cl) * 72 + 32 + quad * 8];
    accS[n16] = __builtin_amdgcn_mfma_f32_16x16x32_bf16(aq0, bk0, accS[n16], 0, 0, 0);
    accS[n16] = __builtin_amdgcn_mfma_f32_16x16x32_bf16(aq1, bk1, accS[n16], 0, 0, 0);
  }

  float mrow[4] = {-1e30f, -1e30f, -1e30f, -1e30f};
#pragma unroll
  for (int r = 0; r < 4; ++r) {
    const float* brow = pbias + ((size_t)h << 16) +
                        (size_t)(qt * 64 + w * 16 + quad * 4 + r) * 256 + cl;
#pragma unroll
    for (int n = 0; n < 16; ++n) {
      float sv = accS[n][r] * 0.125f + brow[n * 16];
      accS[n][r] = sv;
      mrow[r] = fmaxf(mrow[r], sv);
    }
  }
#pragma unroll
  for (int r = 0; r < 4; ++r)
#pragma unroll
    for (int st = 1; st < 16; st <<= 1)
      mrow[r] = fmaxf(mrow[r], __shfl_xor(mrow[r], st));
  float lsum[4] = {0.f, 0.f, 0.f, 0.f};
#pragma unroll
  for (int n = 0; n < 16; ++n)
#pragma unroll
    for (int r = 0; r < 4; ++r) {
      float p = exp2f((accS[n][r] - mrow[r]) * 1.44269504f);
      accS[n][r] = p;
      lsum[r] += p;
    }
#pragma unroll
  for (int r = 0; r < 4; ++r)
#pragma unroll
    for (int st = 1; st < 16; st <<= 1)
      lsum[r] += __shfl_xor(lsum[r], st);

  __syncthreads();

  for (int t = 0; t < 8; ++t) {
    const u16x8 v = *(const u16x8*)&Vt[(tok0 + tid) * 1024 + hc + t * 8];
#pragma unroll
    for (int j = 0; j < 8; ++j) KV[(t * 8 + j) * 264 + tid] = v[j];
  }
  __syncthreads();

  floatx4 accO[4] = {};
#pragma unroll
  for (int hf = 0; hf < 2; ++hf) {
#pragma unroll
    for (int gi = 0; gi < 8; ++gi)
#pragma unroll
      for (int r = 0; r < 4; ++r)
        P[(w * 16 + quad * 4 + r) * 136 + gi * 16 + cl] =
            f2b(accS[hf * 8 + gi][r]);
#pragma unroll
    for (int kk = 0; kk < 4; ++kk) {
      const bf16x8 ap =
          *(const bf16x8*)&P[(w * 16 + cl) * 136 + kk * 32 + quad * 8];
#pragma unroll
      for (int nd = 0; nd < 4; ++nd) {
        const bf16x8 bv = *(const bf16x8*)&KV[(nd * 16 + cl) * 264 +
                                              hf * 128 + kk * 32 + quad * 8];
        accO[nd] = __builtin_amdgcn_mfma_f32_16x16x32_bf16(ap, bv, accO[nd],
                                                           0, 0, 0);
      }
    }
  }

  float inv[4];
#pragma unroll
  for (int r = 0; r < 4; ++r) inv[r] = 1.0f / lsum[r];
#pragma unroll
  for (int nd = 0; nd < 4; ++nd)
#pragma unroll
    for (int r = 0; r < 4; ++r)
      ctx[(qrow0 + w * 16 + quad * 4 + r) * 1024 + hc + nd * 16 + cl] =
          f2b(accO[nd][r] * inv[r]);
}

// ---------------------------------------------------------------------------
// Fused x f32->bf16 conversion + block-mean partial sums (atomic f32)
// ---------------------------------------------------------------------------
__global__ void cvtx_mean(const float* __restrict__ x, u16* __restrict__ xb,
                          float* __restrict__ xmf) {
  const int tq = blockIdx.x;
  const int g  = blockIdx.y;
  const int d0 = threadIdx.x * 4;
  const size_t trow = (size_t)g * 256 + tq * 64;
  const float* p = x + trow * 1024 + d0;
  u16* q = xb + trow * 1024 + d0;
  float4 s = {0.f, 0.f, 0.f, 0.f};
  for (int t = 0; t < 64; ++t) {
    float4 v = *(const float4*)(p + (size_t)t * 1024);
    s.x += v.x; s.y += v.y; s.z += v.z; s.w += v.w;
    u16x4 o;
    o[0] = f2b(v.x); o[1] = f2b(v.y); o[2] = f2b(v.z); o[3] = f2b(v.w);
    *(u16x4*)(q + (size_t)t * 1024) = o;
  }
  atomicAdd(&xmf[g * 1024 + d0 + 0], s.x);
  atomicAdd(&xmf[g * 1024 + d0 + 1], s.y);
  atomicAdd(&xmf[g * 1024 + d0 + 2], s.z);
  atomicAdd(&xmf[g * 1024 + d0 + 3], s.w);
}

__global__ void summ_attn(const u16* __restrict__ SQ, const u16* __restrict__ SK,
                          const u16* __restrict__ SV, u16* __restrict__ sctx) {
  const int b = blockIdx.x >> 4;
  const int h = blockIdx.x & 15;
  const int t = threadIdx.x;  // 64 threads
  __shared__ float Qf[16][64];
  __shared__ float Kf[16][64];
  __shared__ float Vf[16][64];
  __shared__ float sc[16][16];
  for (int i = t; i < 1024; i += 64) {
    const int r = i >> 6, d = i & 63;
    const size_t off = (size_t)(b * 16 + r) * 1024 + h * 64 + d;
    Qf[r][d] = b2f(SQ[off]);
    Kf[r][d] = b2f(SK[off]);
    Vf[r][d] = b2f(SV[off]);
  }
  __syncthreads();
  {
    const int i = t >> 2, j0 = t & 3;
#pragma unroll
    for (int jj = 0; jj < 4; ++jj) {
      const int j = j0 + jj * 4;
      float s = 0.f;
      for (int d = 0; d < 64; ++d) s += Qf[i][d] * Kf[j][d];
      sc[i][j] = s * 0.125f;
    }
  }
  __syncthreads();
  if (t < 16) {
    float m = -1e30f;
    for (int j = 0; j < 16; ++j) m = fmaxf(m, sc[t][j]);
    float l = 0.f;
    for (int j = 0; j < 16; ++j) {
      float p = exp2f((sc[t][j] - m) * 1.44269504f);
      sc[t][j] = p;
      l += p;
    }
    const float inv = 1.0f / l;
    for (int j = 0; j < 16; ++j) sc[t][j] *= inv;
  }
  __syncthreads();
  {
    const int i = t >> 2, d0 = (t & 3) * 16;
    for (int dd = 0; dd < 16; ++dd) {
      float a = 0.f;
      for (int j = 0; j < 16; ++j) a += sc[i][j] * Vf[j][d0 + dd];
      sctx[(size_t)(b * 16 + i) * 1024 + h * 64 + d0 + dd] = f2b(a);
    }
  }
}

// 9x [1024,1024] f32 -> bf16 transposed ("BT": dst[n][k] = src[k][n])
struct TPtrs { const float* src[9]; u16* dst[9]; };

__global__ void cvt_transpose9(TPtrs p) {
  const float* src = p.src[blockIdx.z];
  u16* dst         = p.dst[blockIdx.z];
  __shared__ u16 tile[64][72];
  const int r0 = blockIdx.x * 64, c0 = blockIdx.y * 64;
  for (int i = threadIdx.x; i < 1024; i += 256) {
    const int row = i >> 4, c4 = (i & 15) * 4;
    float4 v = *(const float4*)&src[(size_t)(r0 + row) * 1024 + c0 + c4];
    tile[row][c4 + 0] = f2b(v.x);
    tile[row][c4 + 1] = f2b(v.y);
    tile[row][c4 + 2] = f2b(v.z);
    tile[row][c4 + 3] = f2b(v.w);
  }
  __syncthreads();
  for (int i = threadIdx.x; i < 512; i += 256) {
    const int row = i >> 3, c8 = (i & 7) * 8;
    u16x8 v;
#pragma unroll
    for (int j = 0; j < 8; ++j) v[j] = tile[c8 + j][row];
    *(u16x8*)&dst[(size_t)(c0 + row) * 1024 + r0 + c8] = v;
  }
}

// ---------------------------------------------------------------------------
extern "C" void kernel_launch(void* const* d_in, const int* in_sizes, int n_in,
                              void* d_out, int out_size, void* d_ws, size_t ws_size,
                              hipStream_t stream) {
  const float* x    = (const float*)d_in[0];
  const float* lqw  = (const float*)d_in[1];
  const float* lqb  = (const float*)d_in[2];
  const float* lkw  = (const float*)d_in[3];
  const float* lkb  = (const float*)d_in[4];
  const float* lvw  = (const float*)d_in[5];
  const float* lvb  = (const float*)d_in[6];
  const float* low_ = (const float*)d_in[7];
  const float* lob  = (const float*)d_in[8];
  const float* pb   = (const float*)d_in[9];
  const float* sqw  = (const float*)d_in[10];
  const float* sqb  = (const float*)d_in[11];
  const float* skw  = (const float*)d_in[12];
  const float* skb  = (const float*)d_in[13];
  const float* svw  = (const float*)d_in[14];
  const float* svb  = (const float*)d_in[15];
  const float* sow  = (const float*)d_in[16];
  const float* sob  = (const float*)d_in[17];
  const float* smw  = (const float*)d_in[18];
  const float* smb  = (const float*)d_in[19];

  char* W = (char*)d_ws;
  size_t off = 0;
  u16* wt[9];
  for (int i = 0; i < 9; ++i) { wt[i] = (u16*)(W + off); off += (size_t)1024 * 1024 * 2; }
  u16* Xb    = (u16*)(W + off); off += (size_t)16384 * 1024 * 2;
  float* XMf = (float*)(W + off); off += (size_t)64 * 1024 * 4;
  u16* SMR   = (u16*)(W + off); off += (size_t)64 * 1024 * 2;
  u16* SQp   = (u16*)(W + off); off += (size_t)64 * 1024 * 2;
  u16* SKp   = (u16*)(W + off); off += (size_t)64 * 1024 * 2;
  u16* SVp   = (u16*)(W + off); off += (size_t)64 * 1024 * 2;
  u16* SCT   = (u16*)(W + off); off += (size_t)64 * 1024 * 2;
  float* SMM = (float*)(W + off); off += (size_t)64 * 1024 * 4;
  const size_t fixedB = off;

  int CH = 256;
  for (int c = 16384; c >= 256; c >>= 1) {
    if (fixedB + (size_t)4 * c * 1024 * 2 <= ws_size) { CH = c; break; }
  }
  u16* Qb  = (u16*)(W + fixedB);
  u16* Kb  = Qb + (size_t)CH * 1024;
  u16* Vb  = Kb + (size_t)CH * 1024;
  u16* CTX = Vb + (size_t)CH * 1024;

  TPtrs tp;
  tp.src[0] = lqw; tp.src[1] = lkw; tp.src[2] = lvw; tp.src[3] = low_;
  tp.src[4] = sqw; tp.src[5] = skw; tp.src[6] = svw; tp.src[7] = sow;
  tp.src[8] = smw;
  for (int i = 0; i < 9; ++i) tp.dst[i] = wt[i];
  cvt_transpose9<<<dim3(16, 16, 9), 256, 0, stream>>>(tp);

  hipMemsetAsync(XMf, 0, (size_t)64 * 1024 * 4, stream);
  cvtx_mean<<<dim3(4, 64), 256, 0, stream>>>(x, Xb, XMf);

  SmallArgs s1{};
  s1.A = XMf; s1.BT0 = s1.BT1 = s1.BT2 = wt[8];
  s1.b0 = s1.b1 = s1.b2 = smb;
  s1.a_scale = 1.0f / 256.0f; s1.a_f32 = 1;
  s1.C0 = s1.C1 = s1.C2 = SMR; s1.Cf = nullptr;
  small_gemm<<<dim3(16, 1, 1), 256, 0, stream>>>(s1);

  SmallArgs s2{};
  s2.A = SMR; s2.BT0 = wt[4]; s2.BT1 = wt[5]; s2.BT2 = wt[6];
  s2.b0 = sqb; s2.b1 = skb; s2.b2 = svb;
  s2.a_scale = 1.0f; s2.a_f32 = 0;
  s2.C0 = SQp; s2.C1 = SKp; s2.C2 = SVp; s2.Cf = nullptr;
  small_gemm<<<dim3(16, 1, 3), 256, 0, stream>>>(s2);

  summ_attn<<<dim3(64), 64, 0, stream>>>(SQp, SKp, SVp, SCT);

  SmallArgs s3{};
  s3.A = SCT; s3.BT0 = s3.BT1 = s3.BT2 = wt[7];
  s3.b0 = s3.b1 = s3.b2 = sob;
  s3.a_scale = 1.0f; s3.a_f32 = 0;
  s3.C0 = s3.C1 = s3.C2 = nullptr; s3.Cf = SMM;
  small_gemm<<<dim3(16, 1, 1), 256, 0, stream>>>(s3);

  for (int base = 0; base < 16384; base += CH) {
    GemmArgs g4{};
    g4.A = Xb + (size_t)base * 1024;
    g4.BT0 = wt[0]; g4.BT1 = wt[1]; g4.BT2 = wt[2];
    g4.b0 = lqb; g4.b1 = lkb; g4.b2 = lvb; g4.summ = nullptr; g4.srow0 = 0;
    g4.C0 = Qb; g4.C1 = Kb; g4.C2 = Vb; g4.Cf = nullptr;
    gemm_bt<<<dim3(CH / 128, 8, 3), 256, 0, stream>>>(g4);

    local_attn<<<dim3(4, 16, CH / 256), 256, 0, stream>>>(Qb, Kb, Vb, pb, CTX);

    GemmArgs g5{};
    g5.A = CTX; g5.BT0 = g5.BT1 = g5.BT2 = wt[3];
    g5.b0 = g5.b1 = g5.b2 = lob; g5.summ = SMM; g5.srow0 = base >> 8;
    g5.C0 = g5.C1 = g5.C2 = nullptr;
    g5.Cf = (float*)d_out + (size_t)base * 1024;
    gemm_bt<<<dim3(CH / 128, 8, 1), 256, 0, stream>>>(g5);
  }

  (void)in_sizes; (void)n_in; (void)out_size;
}